// Round 5
// baseline (300.599 us; speedup 1.0000x reference)
//
#include <hip/hip_runtime.h>
#include <math.h>

// Problem constants: B=1, CIN=COUT=32, KS=3 (K=27), D=32, H=W=64, stride=1, pad=1, dil=1
#define DD 32
#define HH 64
#define WW 64
#define CSTRIDE (DD * HH * WW)   // 131072
#define NPOS (DD * HH * WW)

// Padded xT geometry: breaks power-of-2 L1 set aliasing on y/z steps.
// y-stride = 65 pos * 64 B = 4160 B (bit6 varies); z-stride = 4184*64 =
// 267776 B = 0x41600 (bits 9/10 vary). Pad cells are never read: all
// sampled/clamped coords land in x<64, y<64, z<32.
#define PITCH 65
#define PLANE (HH * PITCH + 24)   // 4184 positions per z-slice
#define XTPOS (DD * PLANE)        // 133888 positions total (8.57 MB)

typedef __attribute__((ext_vector_type(8))) short  short8;   // 8 bf16 (4 VGPRs) MFMA A/B frag
typedef __attribute__((ext_vector_type(4))) float  float4v;  // MFMA C/D frag
typedef __attribute__((ext_vector_type(2))) float  f2v;      // packed-f32 pair
typedef __attribute__((ext_vector_type(4))) unsigned int uint4v;
typedef __attribute__((ext_vector_type(2))) unsigned int uint2v;

__device__ __forceinline__ unsigned short f2bf(float f) {
    unsigned u = __builtin_bit_cast(unsigned, f);
    u = u + 0x7FFFu + ((u >> 16) & 1u);        // round-to-nearest-even
    return (unsigned short)(u >> 16);
}

// unpack one dword holding 2 bf16 -> f2v {lo, hi} (1 shift + 1 and)
__device__ __forceinline__ f2v bfpair(unsigned u) {
    f2v r;
    r.x = __builtin_bit_cast(float, u << 16);
    r.y = __builtin_bit_cast(float, u & 0xFFFF0000u);
    return r;
}

// fp16 pack/unpack
__device__ __forceinline__ unsigned pkh(float a, float b) {
    unsigned short ua = __builtin_bit_cast(unsigned short, (_Float16)a);
    unsigned short ub = __builtin_bit_cast(unsigned short, (_Float16)b);
    return (unsigned)ua | ((unsigned)ub << 16);
}
__device__ __forceinline__ float h2f(unsigned short u) {
    return (float)__builtin_bit_cast(_Float16, u);
}

// ---------------------------------------------------------------------------
// prep_all: fused prep_x + prep_w. xT written at PADDED positions.
// ---------------------------------------------------------------------------
__global__ __launch_bounds__(256) void prep_all(
    const float* __restrict__ x, unsigned short* __restrict__ xT,
    const float* __restrict__ w_off, const float* __restrict__ w_mask,
    const float* __restrict__ w,
    unsigned short* __restrict__ wAc, unsigned short* __restrict__ wAe)
{
    if (blockIdx.x < NPOS / 256) {
        int pos = blockIdx.x * 256 + threadIdx.x;      // compact index
        int z = pos >> 12, y = (pos >> 6) & 63, xx = pos & 63;
        int ppos = z * PLANE + y * PITCH + xx;         // padded index
        float v[32];
#pragma unroll
        for (int ci = 0; ci < 32; ci++) v[ci] = x[ci * CSTRIDE + pos];
        unsigned dw[16];
#pragma unroll
        for (int p = 0; p < 16; p++)
            asm("v_cvt_pk_bf16_f32 %0, %1, %2"
                : "=v"(dw[p]) : "v"(v[2 * p]), "v"(v[2 * p + 1]));
        uint4v* dst = (uint4v*)(xT + (size_t)ppos * 32);
#pragma unroll
        for (int o = 0; o < 4; o++) {
            uint4v t4 = {dw[4 * o], dw[4 * o + 1], dw[4 * o + 2], dw[4 * o + 3]};
            dst[o] = t4;
        }
    } else {
        int i = (blockIdx.x - NPOS / 256) * 256 + threadIdx.x;
        if (i < 27 * 7 * 64 * 8) {                       // 96768: conv A-frags
            int j    = i & 7;
            int lane = (i >> 3) & 63;
            int fm   = i >> 9;
            int mt   = fm % 7;
            int tapw = fm / 7;                           // conv kernel tap
            int ch   = mt * 16 + (lane & 15);            // ch' = tap_o*4+comp
            int ci   = (lane >> 4) * 8 + j;
            float v = 0.f;
            if (ch < 108) {
                int tapo = ch >> 2, comp = ch & 3;
                v = (comp < 3) ? w_off[((comp * 27 + tapo) * 32 + ci) * 27 + tapw]
                               : w_mask[(tapo * 32 + ci) * 27 + tapw];
            }
            wAc[i] = f2bf(v);
        } else {                                         // 27648: einsum A-frags
            int i2   = i - 27 * 7 * 64 * 8;
            int j    = i2 & 7;
            int lane = (i2 >> 3) & 63;
            int fm   = i2 >> 9;
            int mt   = fm % 2;
            int tapw = fm / 2;
            int co   = mt * 16 + (lane & 15);
            int ci   = (lane >> 4) * 8 + j;
            wAe[i2] = f2bf(w[(co * 32 + ci) * 27 + tapw]);
        }
    }
}

// ---------------------------------------------------------------------------
// conv_offm: offset/mask conv. B-loads use padded xT addressing.
// ---------------------------------------------------------------------------
__global__ __launch_bounds__(256, 5) void conv_offm(
    const unsigned short* __restrict__ xT,
    const unsigned short* __restrict__ wAc,
    const float* __restrict__ b_off, const float* __restrict__ b_mask,
    unsigned int* __restrict__ offmH)
{
    int bid = blockIdx.x;
    int swz = (bid & 7) * 128 + (bid >> 3);        // 8 XCD chunks of 128
    const int t = threadIdx.x, lane = t & 63;
    const int wv = t >> 6, wl = lane & 15, q = lane >> 4;
    const int row = swz * 2 + (wv >> 1);
    const int z = row >> 6, y = row & 63;
    const int xb = (wv & 1) * 32;

    float4v acc[7][2];
#pragma unroll
    for (int mt = 0; mt < 7; mt++)
#pragma unroll
        for (int nt = 0; nt < 2; nt++)
            acc[mt][nt] = (float4v){0.f, 0.f, 0.f, 0.f};

    for (int kz = 0; kz < 3; kz++) {
        int zs = z + kz - 1;
        bool zok = (unsigned)zs < (unsigned)DD;
        int zc = min(max(zs, 0), DD - 1);
#pragma unroll
        for (int j = 0; j < 9; j++) {
            const int ky = j / 3, kx = j % 3;
            int tap = kz * 9 + j;
            int ys = y + ky - 1;
            bool yok = (unsigned)ys < (unsigned)HH;
            int yc = min(max(ys, 0), HH - 1);
            int rowp = zc * PLANE + yc * PITCH;    // padded

            short8 b0, b1;
#pragma unroll
            for (int nt = 0; nt < 2; nt++) {
                int xs = xb + nt * 16 + wl + kx - 1;
                bool ok = zok & yok & ((unsigned)xs < (unsigned)WW);
                int xc = min(max(xs, 0), WW - 1);
                short8 bb = *(const short8*)(xT + (size_t)(rowp + xc) * 32 + q * 8);
                if (!ok) bb = (short8)0;
                if (nt == 0) b0 = bb; else b1 = bb;
            }

            const unsigned short* ap = wAc + (size_t)tap * 3584 + lane * 8;
#pragma unroll
            for (int mt = 0; mt < 7; mt++) {
                short8 a = *(const short8*)(ap + mt * 512);
                acc[mt][0] = __builtin_amdgcn_mfma_f32_16x16x32_bf16(a, b0, acc[mt][0], 0, 0, 0);
                acc[mt][1] = __builtin_amdgcn_mfma_f32_16x16x32_bf16(a, b1, acc[mt][1], 0, 0, 0);
            }
        }
    }

    const int rowpos = row * WW;                   // compact out index
#pragma unroll
    for (int mt = 0; mt < 7; mt++) {
        int tapo = mt * 4 + q;
        if (tapo < 27) {
            float bz = b_off[tapo], by = b_off[27 + tapo], bx = b_off[54 + tapo];
            float bm = b_mask[tapo];
#pragma unroll
            for (int nt = 0; nt < 2; nt++) {
                float4v v = acc[mt][nt];
                float mm = v.w + bm;
                mm = 1.f / (1.f + __expf(-mm));
                int posn = rowpos + xb + nt * 16 + wl;
                uint2v pk = { pkh(v.x + bz, v.y + by), pkh(v.z + bx, mm) };
                *(uint2v*)(offmH + ((size_t)tapo * NPOS + posn) * 2) = pk;
            }
        }
    }
}

// ---------------------------------------------------------------------------
// sample_einsum (r2 structure + padded gathers): LDS-free / barrier-free.
// Grid = 2048 blocks (XCD-chunk swizzled), 4 independent waves, one (d,h)
// row per block, wave wv owns wcols [wv*16, wv*16+16).
// ---------------------------------------------------------------------------
__global__ __launch_bounds__(256, 6) void sample_einsum(
    const unsigned short* __restrict__ xT,
    const unsigned short* __restrict__ wAe,
    const unsigned int* __restrict__ offmH,
    const float* __restrict__ bias, float* __restrict__ out)
{
    int bid = blockIdx.x;
    int swz = (bid & 7) * 256 + (bid >> 3);        // 8 XCD chunks of 256 rows
    const int t = threadIdx.x, lane = t & 63;
    const int wv = t >> 6, wl = lane & 15, q = lane >> 4;
    const int d = swz >> 6, h = swz & 63;
    const int wcol = wv * 16 + wl;
    const int pos = (d * HH + h) * WW + wcol;      // compact (offm/out)

    const unsigned short* xTq  = xT + q * 8;
    const unsigned short* wAeL = wAe + (size_t)lane * 8;
    float4v ac0 = (float4v){0.f, 0.f, 0.f, 0.f};
    float4v ac1 = (float4v){0.f, 0.f, 0.f, 0.f};

    for (int kz = 0; kz < 3; kz++) {
        float zbase = (float)(d + kz - 1);
#pragma unroll
        for (int j = 0; j < 9; j++) {
            const int ky = j / 3, kx = j % 3;      // compile-time
            int tap = kz * 9 + j;

            uint2v om = *(const uint2v*)(offmH + ((size_t)tap * NPOS + pos) * 2);
            float zc = zbase + h2f((unsigned short)(om.x & 0xFFFF));
            float yc = (float)(h + ky - 1) + h2f((unsigned short)(om.x >> 16));
            float xc = (float)(wcol + kx - 1) + h2f((unsigned short)(om.y & 0xFFFF));
            float m  = h2f((unsigned short)(om.y >> 16));

            float zf = floorf(zc), yf = floorf(yc), xf = floorf(xc);
            int z0 = (int)zf, y0 = (int)yf, x0 = (int)xf;
            float fz = zc - zf, fy = yc - yf, fx = xc - xf;

            float wz0 = (z0 >= 0 && z0 < DD)         ? (1.f - fz) : 0.f;
            float wz1 = (z0 + 1 >= 0 && z0 + 1 < DD) ? fz         : 0.f;
            float wy0 = (y0 >= 0 && y0 < HH)         ? (1.f - fy) : 0.f;
            float wy1 = (y0 + 1 >= 0 && y0 + 1 < HH) ? fy         : 0.f;
            float wx0 = (x0 >= 0 && x0 < WW)         ? (1.f - fx) : 0.f;
            float wx1 = (x0 + 1 >= 0 && x0 + 1 < WW) ? fx         : 0.f;

            float mz0 = m * wz0, mz1 = m * wz1;
            float a00 = mz0 * wy0, a01 = mz0 * wy1, a10 = mz1 * wy0, a11 = mz1 * wy1;
            float cw[8];
            cw[0] = a00 * wx0; cw[1] = a00 * wx1; cw[2] = a01 * wx0; cw[3] = a01 * wx1;
            cw[4] = a10 * wx0; cw[5] = a10 * wx1; cw[6] = a11 * wx0; cw[7] = a11 * wx1;

            int iz0 = min(max(z0, 0), DD - 1), iz1 = min(max(z0 + 1, 0), DD - 1);
            int iy0 = min(max(y0, 0), HH - 1), iy1 = min(max(y0 + 1, 0), HH - 1);
            int ix0 = min(max(x0, 0), WW - 1), ix1 = min(max(x0 + 1, 0), WW - 1);
            int o00 = iz0 * PLANE + iy0 * PITCH, o01 = iz0 * PLANE + iy1 * PITCH;
            int o10 = iz1 * PLANE + iy0 * PITCH, o11 = iz1 * PLANE + iy1 * PITCH;

            short8 cnr[8];
            cnr[0] = *(const short8*)(xTq + (o00 + ix0) * 32);
            cnr[1] = *(const short8*)(xTq + (o00 + ix1) * 32);
            cnr[2] = *(const short8*)(xTq + (o01 + ix0) * 32);
            cnr[3] = *(const short8*)(xTq + (o01 + ix1) * 32);
            cnr[4] = *(const short8*)(xTq + (o10 + ix0) * 32);
            cnr[5] = *(const short8*)(xTq + (o10 + ix1) * 32);
            cnr[6] = *(const short8*)(xTq + (o11 + ix0) * 32);
            cnr[7] = *(const short8*)(xTq + (o11 + ix1) * 32);

            f2v v0 = {0.f, 0.f}, v1 = {0.f, 0.f}, v2 = {0.f, 0.f}, v3 = {0.f, 0.f};
#pragma unroll
            for (int c = 0; c < 8; c++) {
                uint4v u = __builtin_bit_cast(uint4v, cnr[c]);
                f2v w2; w2.x = cw[c]; w2.y = cw[c];
                v0 += bfpair(u.x) * w2;
                v1 += bfpair(u.y) * w2;
                v2 += bfpair(u.z) * w2;
                v3 += bfpair(u.w) * w2;
            }

            unsigned r0, r1, r2, r3;
            asm("v_cvt_pk_bf16_f32 %0, %1, %2" : "=v"(r0) : "v"(v0.x), "v"(v0.y));
            asm("v_cvt_pk_bf16_f32 %0, %1, %2" : "=v"(r1) : "v"(v1.x), "v"(v1.y));
            asm("v_cvt_pk_bf16_f32 %0, %1, %2" : "=v"(r2) : "v"(v2.x), "v"(v2.y));
            asm("v_cvt_pk_bf16_f32 %0, %1, %2" : "=v"(r3) : "v"(v3.x), "v"(v3.y));
            uint4v pr = {r0, r1, r2, r3};
            short8 bfr = __builtin_bit_cast(short8, pr);

            const unsigned short* aep = wAeL + (size_t)tap * 1024;
            short8 a0 = *(const short8*)(aep);
            short8 a1 = *(const short8*)(aep + 512);
            ac0 = __builtin_amdgcn_mfma_f32_16x16x32_bf16(a0, bfr, ac0, 0, 0, 0);
            ac1 = __builtin_amdgcn_mfma_f32_16x16x32_bf16(a1, bfr, ac1, 0, 0, 0);
        }
    }

    // epilogue: C/D layout col = lane&15 (w), row = q*4+r (co)
    int sp = pos;
#pragma unroll
    for (int r = 0; r < 4; r++) {
        int co0 = q * 4 + r;
        out[co0 * CSTRIDE + sp]        = ac0[r] + bias[co0];
        out[(16 + co0) * CSTRIDE + sp] = ac1[r] + bias[16 + co0];
    }
}

// ---------------------------------------------------------------------------
extern "C" void kernel_launch(void* const* d_in, const int* in_sizes, int n_in,
                              void* d_out, int out_size, void* d_ws, size_t ws_size,
                              hipStream_t stream) {
    const float* x      = (const float*)d_in[0];
    const float* w_off  = (const float*)d_in[1];
    const float* b_off  = (const float*)d_in[2];
    const float* w_mask = (const float*)d_in[3];
    const float* b_mask = (const float*)d_in[4];
    const float* w      = (const float*)d_in[5];
    const float* b      = (const float*)d_in[6];
    float* out = (float*)d_out;

    // workspace layout (16B aligned):
    //   xT    8,568,832 B   bf16 x[padded pos][32ch]  (PITCH=65, PLANE=4184)
    //   wAc     193,536 B   conv A-frags
    //   wAe      55,296 B   einsum A-frags
    //   offmH 28,311,552 B  fp16x4 {oz,oy,ox,mask}[tap][pos]   (total ~37.1 MB)
    unsigned short* xT  = (unsigned short*)d_ws;
    unsigned short* wAc = xT + (size_t)XTPOS * 32;
    unsigned short* wAe = wAc + 27 * 7 * 64 * 8;
    unsigned int* offmH = (unsigned int*)(wAe + 27 * 2 * 64 * 8);

    hipLaunchKernelGGL(prep_all, dim3(NPOS / 256 + 486), dim3(256), 0, stream,
                       x, xT, w_off, w_mask, w, wAc, wAe);
    hipLaunchKernelGGL(conv_offm, dim3(1024), dim3(256), 0, stream,
                       xT, wAc, b_off, b_mask, offmH);
    hipLaunchKernelGGL(sample_einsum, dim3(2048), dim3(256), 0, stream,
                       xT, wAe, offmH, b, out);
}

// Round 6
// 288.568 us; speedup vs baseline: 1.0417x; 1.0417x over previous
//
#include <hip/hip_runtime.h>
#include <math.h>

// Problem constants: B=1, CIN=COUT=32, KS=3 (K=27), D=32, H=W=64, stride=1, pad=1, dil=1
#define DD 32
#define HH 64
#define WW 64
#define CSTRIDE (DD * HH * WW)   // 131072
#define NPOS (DD * HH * WW)

typedef __attribute__((ext_vector_type(8))) short  short8;      // 16B load vehicle
typedef _Float16 __attribute__((ext_vector_type(8))) half8;     // 8 fp16 MFMA A/B frag
typedef __attribute__((ext_vector_type(4))) float  float4v;     // MFMA C/D frag
typedef __attribute__((ext_vector_type(2))) float  f2v;
typedef __attribute__((ext_vector_type(4))) unsigned int uint4v;
typedef __attribute__((ext_vector_type(2))) unsigned int uint2v;

__device__ __forceinline__ unsigned short f2h(float f) {
    return __builtin_bit_cast(unsigned short, (_Float16)f);
}
__device__ __forceinline__ float h2f(unsigned short u) {
    return (float)__builtin_bit_cast(_Float16, u);
}
__device__ __forceinline__ unsigned pkh(float a, float b) {
    return (unsigned)f2h(a) | ((unsigned)f2h(b) << 16);
}
__device__ __forceinline__ float4v mfma16(half8 a, half8 b, float4v c) {
    return __builtin_amdgcn_mfma_f32_16x16x32_f16(a, b, c, 0, 0, 0);
}

// ---------------------------------------------------------------------------
// prep_all: fused prep_x + prep_w — fp16 pipeline, compact xT (padding
// reverted: r5 proved it null and it cost FETCH).
//  blocks [0,512):    x[ci][pos] fp32 -> xT[pos][32ch] fp16 (64 B/pos)
//  blocks [512,998):  weight swizzles (fp16). wAc ch' = tap_o*4+comp.
// ---------------------------------------------------------------------------
__global__ __launch_bounds__(256) void prep_all(
    const float* __restrict__ x, unsigned short* __restrict__ xT,
    const float* __restrict__ w_off, const float* __restrict__ w_mask,
    const float* __restrict__ w,
    unsigned short* __restrict__ wAc, unsigned short* __restrict__ wAe)
{
    if (blockIdx.x < NPOS / 256) {
        int pos = blockIdx.x * 256 + threadIdx.x;
        float v[32];
#pragma unroll
        for (int ci = 0; ci < 32; ci++) v[ci] = x[ci * CSTRIDE + pos];
        unsigned dw[16];
#pragma unroll
        for (int p = 0; p < 16; p++)
            dw[p] = (unsigned)f2h(v[2 * p]) | ((unsigned)f2h(v[2 * p + 1]) << 16);
        uint4v* dst = (uint4v*)(xT + (size_t)pos * 32);
#pragma unroll
        for (int o = 0; o < 4; o++) {
            uint4v t4 = {dw[4 * o], dw[4 * o + 1], dw[4 * o + 2], dw[4 * o + 3]};
            dst[o] = t4;
        }
    } else {
        int i = (blockIdx.x - NPOS / 256) * 256 + threadIdx.x;
        if (i < 27 * 7 * 64 * 8) {                       // 96768: conv A-frags
            int j    = i & 7;
            int lane = (i >> 3) & 63;
            int fm   = i >> 9;
            int mt   = fm % 7;
            int tapw = fm / 7;                           // conv kernel tap
            int ch   = mt * 16 + (lane & 15);            // ch' = tap_o*4+comp
            int ci   = (lane >> 4) * 8 + j;
            float v = 0.f;
            if (ch < 108) {
                int tapo = ch >> 2, comp = ch & 3;
                v = (comp < 3) ? w_off[((comp * 27 + tapo) * 32 + ci) * 27 + tapw]
                               : w_mask[(tapo * 32 + ci) * 27 + tapw];
            }
            wAc[i] = f2h(v);
        } else {                                         // 27648: einsum A-frags
            int i2   = i - 27 * 7 * 64 * 8;
            int j    = i2 & 7;
            int lane = (i2 >> 3) & 63;
            int fm   = i2 >> 9;
            int mt   = fm % 2;
            int tapw = fm / 2;
            int co   = mt * 16 + (lane & 15);
            int ci   = (lane >> 4) * 8 + j;
            wAe[i2] = f2h(w[(co * 32 + ci) * 27 + tapw]);
        }
    }
}

// ---------------------------------------------------------------------------
// conv_offm: offset/mask conv via fp16 MFMA (structure unchanged from r2).
// Output offmH[tap][pos] = packed {f16 oz,oy,ox,mask}, tap-major (as r2/r5).
// ---------------------------------------------------------------------------
__global__ __launch_bounds__(256, 5) void conv_offm(
    const unsigned short* __restrict__ xT,
    const unsigned short* __restrict__ wAc,
    const float* __restrict__ b_off, const float* __restrict__ b_mask,
    unsigned int* __restrict__ offmH)
{
    int bid = blockIdx.x;
    int swz = (bid & 7) * 128 + (bid >> 3);        // 8 XCD chunks of 128
    const int t = threadIdx.x, lane = t & 63;
    const int wv = t >> 6, wl = lane & 15, q = lane >> 4;
    const int row = swz * 2 + (wv >> 1);
    const int z = row >> 6, y = row & 63;
    const int xb = (wv & 1) * 32;

    float4v acc[7][2];
#pragma unroll
    for (int mt = 0; mt < 7; mt++)
#pragma unroll
        for (int nt = 0; nt < 2; nt++)
            acc[mt][nt] = (float4v){0.f, 0.f, 0.f, 0.f};

    for (int kz = 0; kz < 3; kz++) {
        int zs = z + kz - 1;
        bool zok = (unsigned)zs < (unsigned)DD;
        int zc = min(max(zs, 0), DD - 1);
#pragma unroll
        for (int j = 0; j < 9; j++) {
            const int ky = j / 3, kx = j % 3;
            int tap = kz * 9 + j;
            int ys = y + ky - 1;
            bool yok = (unsigned)ys < (unsigned)HH;
            int yc = min(max(ys, 0), HH - 1);
            int rowp = (zc * HH + yc) * WW;

            short8 b0, b1;
#pragma unroll
            for (int nt = 0; nt < 2; nt++) {
                int xs = xb + nt * 16 + wl + kx - 1;
                bool ok = zok & yok & ((unsigned)xs < (unsigned)WW);
                int xc = min(max(xs, 0), WW - 1);
                short8 bb = *(const short8*)(xT + (size_t)(rowp + xc) * 32 + q * 8);
                if (!ok) bb = (short8)0;
                if (nt == 0) b0 = bb; else b1 = bb;
            }

            const unsigned short* ap = wAc + (size_t)tap * 3584 + lane * 8;
#pragma unroll
            for (int mt = 0; mt < 7; mt++) {
                half8 a = __builtin_bit_cast(half8, *(const short8*)(ap + mt * 512));
                acc[mt][0] = mfma16(a, __builtin_bit_cast(half8, b0), acc[mt][0]);
                acc[mt][1] = mfma16(a, __builtin_bit_cast(half8, b1), acc[mt][1]);
            }
        }
    }

    const int rowpos = row * WW;
#pragma unroll
    for (int mt = 0; mt < 7; mt++) {
        int tapo = mt * 4 + q;
        if (tapo < 27) {
            float bz = b_off[tapo], by = b_off[27 + tapo], bx = b_off[54 + tapo];
            float bm = b_mask[tapo];
#pragma unroll
            for (int nt = 0; nt < 2; nt++) {
                float4v v = acc[mt][nt];
                float mm = v.w + bm;
                mm = 1.f / (1.f + __expf(-mm));
                int posn = rowpos + xb + nt * 16 + wl;
                uint2v pk = { pkh(v.x + bz, v.y + by), pkh(v.z + bx, mm) };
                *(uint2v*)(offmH + ((size_t)tapo * NPOS + posn) * 2) = pk;
            }
        }
    }
}

// ---------------------------------------------------------------------------
// sample_einsum v6: interp-free corner-MFMA formulation.
//   out[co] = sum_c sum_ci w[co,ci,tap] * (cw_c * x[ci,corner_c])
// Each corner's raw fp16 gather data is scaled by its trilerp weight with
// 4 v_pk_mul_f16 and fed straight into the MFMA B operand — the ~100-instr
// unpack/interp/repack chain per tap is gone; the matrix pipe (1.6% busy)
// absorbs 16 MFMA/tap into 4 accumulators (no dependent-MFMA chaining).
// offm is register-prefetched 1 tap ahead (branch-free) to hoist its HBM
// latency off the per-tap chain head.
// ---------------------------------------------------------------------------
__global__ __launch_bounds__(256, 4) void sample_einsum(
    const unsigned short* __restrict__ xT,
    const unsigned short* __restrict__ wAe,
    const unsigned int* __restrict__ offmH,
    const float* __restrict__ bias, float* __restrict__ out)
{
    int bid = blockIdx.x;
    int swz = (bid & 7) * 256 + (bid >> 3);        // 8 XCD chunks of 256 rows
    const int t = threadIdx.x, lane = t & 63;
    const int wv = t >> 6, wl = lane & 15, q = lane >> 4;
    const int d = swz >> 6, h = swz & 63;
    const int wcol = wv * 16 + wl;
    const int pos = (d * HH + h) * WW + wcol;

    const unsigned short* xTq  = xT + q * 8;
    const unsigned short* wAeL = wAe + (size_t)lane * 8;
    float4v accA0 = (float4v){0.f, 0.f, 0.f, 0.f};
    float4v accA1 = (float4v){0.f, 0.f, 0.f, 0.f};
    float4v accB0 = (float4v){0.f, 0.f, 0.f, 0.f};
    float4v accB1 = (float4v){0.f, 0.f, 0.f, 0.f};

    // prefetch offm for tap 0
    uint2v omc = *(const uint2v*)(offmH + (size_t)pos * 2);

    for (int kz = 0; kz < 3; kz++) {
        float zbase = (float)(d + kz - 1);
#pragma unroll
        for (int j = 0; j < 9; j++) {
            const int ky = j / 3, kx = j % 3;      // compile-time
            int tap = kz * 9 + j;

            // prefetch next tap's offm (clamped -> branch-free, last is redundant)
            int tapn = min(tap + 1, 26);
            uint2v omn = *(const uint2v*)(offmH + ((size_t)tapn * NPOS + pos) * 2);

            float zc = zbase + h2f((unsigned short)(omc.x & 0xFFFF));
            float yc = (float)(h + ky - 1) + h2f((unsigned short)(omc.x >> 16));
            float xc = (float)(wcol + kx - 1) + h2f((unsigned short)(omc.y & 0xFFFF));
            float m  = h2f((unsigned short)(omc.y >> 16));

            float zf = floorf(zc), yf = floorf(yc), xf = floorf(xc);
            int z0 = (int)zf, y0 = (int)yf, x0 = (int)xf;
            float fz = zc - zf, fy = yc - yf, fx = xc - xf;

            float wz0 = (z0 >= 0 && z0 < DD)         ? (1.f - fz) : 0.f;
            float wz1 = (z0 + 1 >= 0 && z0 + 1 < DD) ? fz         : 0.f;
            float wy0 = (y0 >= 0 && y0 < HH)         ? (1.f - fy) : 0.f;
            float wy1 = (y0 + 1 >= 0 && y0 + 1 < HH) ? fy         : 0.f;
            float wx0 = (x0 >= 0 && x0 < WW)         ? (1.f - fx) : 0.f;
            float wx1 = (x0 + 1 >= 0 && x0 + 1 < WW) ? fx         : 0.f;

            float mz0 = m * wz0, mz1 = m * wz1;
            float a00 = mz0 * wy0, a01 = mz0 * wy1, a10 = mz1 * wy0, a11 = mz1 * wy1;
            float cw[8];
            cw[0] = a00 * wx0; cw[1] = a00 * wx1; cw[2] = a01 * wx0; cw[3] = a01 * wx1;
            cw[4] = a10 * wx0; cw[5] = a10 * wx1; cw[6] = a11 * wx0; cw[7] = a11 * wx1;

            int iz0 = min(max(z0, 0), DD - 1), iz1 = min(max(z0 + 1, 0), DD - 1);
            int iy0 = min(max(y0, 0), HH - 1), iy1 = min(max(y0 + 1, 0), HH - 1);
            int ix0 = min(max(x0, 0), WW - 1), ix1 = min(max(x0 + 1, 0), WW - 1);
            int o00 = (iz0 * HH + iy0) * WW, o01 = (iz0 * HH + iy1) * WW;
            int o10 = (iz1 * HH + iy0) * WW, o11 = (iz1 * HH + iy1) * WW;

            short8 cnr[8];
            cnr[0] = *(const short8*)(xTq + (o00 + ix0) * 32);
            cnr[1] = *(const short8*)(xTq + (o00 + ix1) * 32);
            cnr[2] = *(const short8*)(xTq + (o01 + ix0) * 32);
            cnr[3] = *(const short8*)(xTq + (o01 + ix1) * 32);
            cnr[4] = *(const short8*)(xTq + (o10 + ix0) * 32);
            cnr[5] = *(const short8*)(xTq + (o10 + ix1) * 32);
            cnr[6] = *(const short8*)(xTq + (o11 + ix0) * 32);
            cnr[7] = *(const short8*)(xTq + (o11 + ix1) * 32);

            const unsigned short* aep = wAeL + (size_t)tap * 1024;
            half8 a0 = __builtin_bit_cast(half8, *(const short8*)(aep));
            half8 a1 = __builtin_bit_cast(half8, *(const short8*)(aep + 512));

#pragma unroll
            for (int c = 0; c < 8; c++) {
                _Float16 ch = (_Float16)cw[c];
                half8 bh = __builtin_bit_cast(half8, cnr[c]) * ch;   // 4x v_pk_mul_f16
                if (c < 4) {
                    accA0 = mfma16(a0, bh, accA0);
                    accA1 = mfma16(a1, bh, accA1);
                } else {
                    accB0 = mfma16(a0, bh, accB0);
                    accB1 = mfma16(a1, bh, accB1);
                }
            }

            omc = omn;
        }
    }

    // epilogue: merge accumulator banks; C/D layout col = lane&15, row = q*4+r
    int sp = pos;
#pragma unroll
    for (int r = 0; r < 4; r++) {
        int co0 = q * 4 + r;
        out[co0 * CSTRIDE + sp]        = accA0[r] + accB0[r] + bias[co0];
        out[(16 + co0) * CSTRIDE + sp] = accA1[r] + accB1[r] + bias[16 + co0];
    }
}

// ---------------------------------------------------------------------------
extern "C" void kernel_launch(void* const* d_in, const int* in_sizes, int n_in,
                              void* d_out, int out_size, void* d_ws, size_t ws_size,
                              hipStream_t stream) {
    const float* x      = (const float*)d_in[0];
    const float* w_off  = (const float*)d_in[1];
    const float* b_off  = (const float*)d_in[2];
    const float* w_mask = (const float*)d_in[3];
    const float* b_mask = (const float*)d_in[4];
    const float* w      = (const float*)d_in[5];
    const float* b      = (const float*)d_in[6];
    float* out = (float*)d_out;

    // workspace layout (16B aligned, ~37.0 MB total — same budget as r2):
    //   xT    8,388,608 B   fp16 x[pos][32ch]
    //   wAc     193,536 B   conv A-frags (fp16)
    //   wAe      55,296 B   einsum A-frags (fp16)
    //   offmH 28,311,552 B  fp16x4 {oz,oy,ox,mask}[tap][pos]
    unsigned short* xT  = (unsigned short*)d_ws;
    unsigned short* wAc = xT + (size_t)NPOS * 32;
    unsigned short* wAe = wAc + 27 * 7 * 64 * 8;
    unsigned int* offmH = (unsigned int*)(wAe + 27 * 2 * 64 * 8);

    hipLaunchKernelGGL(prep_all, dim3(NPOS / 256 + 486), dim3(256), 0, stream,
                       x, xT, w_off, w_mask, w, wAc, wAe);
    hipLaunchKernelGGL(conv_offm, dim3(1024), dim3(256), 0, stream,
                       xT, wAc, b_off, b_mask, offmH);
    hipLaunchKernelGGL(sample_einsum, dim3(2048), dim3(256), 0, stream,
                       xT, wAe, offmH, b, out);
}

// Round 8
// 263.803 us; speedup vs baseline: 1.1395x; 1.0939x over previous
//
#include <hip/hip_runtime.h>
#include <math.h>

// Problem constants: B=1, CIN=COUT=32, KS=3 (K=27), D=32, H=W=64, stride=1, pad=1, dil=1
#define DD 32
#define HH 64
#define WW 64
#define CSTRIDE (DD * HH * WW)   // 131072
#define NPOS (DD * HH * WW)

typedef __attribute__((ext_vector_type(8))) short  short8;      // 16B load vehicle
typedef _Float16 __attribute__((ext_vector_type(8))) half8;     // 8 fp16 MFMA A/B frag
typedef __attribute__((ext_vector_type(4))) float  float4v;     // MFMA C/D frag
typedef __attribute__((ext_vector_type(2))) float  f2v;
typedef __attribute__((ext_vector_type(4))) unsigned int uint4v;
typedef __attribute__((ext_vector_type(2))) unsigned int uint2v;

__device__ __forceinline__ unsigned short f2h(float f) {
    return __builtin_bit_cast(unsigned short, (_Float16)f);
}
__device__ __forceinline__ float h2f(unsigned short u) {
    return (float)__builtin_bit_cast(_Float16, u);
}
__device__ __forceinline__ unsigned pkh(float a, float b) {
    return (unsigned)f2h(a) | ((unsigned)f2h(b) << 16);
}
__device__ __forceinline__ float4v mfma16(half8 a, half8 b, float4v c) {
    return __builtin_amdgcn_mfma_f32_16x16x32_f16(a, b, c, 0, 0, 0);
}

// ---------------------------------------------------------------------------
// prep_all: fused prep_x + prep_w — unchanged from r6 (fp16 pipeline).
// ---------------------------------------------------------------------------
__global__ __launch_bounds__(256) void prep_all(
    const float* __restrict__ x, unsigned short* __restrict__ xT,
    const float* __restrict__ w_off, const float* __restrict__ w_mask,
    const float* __restrict__ w,
    unsigned short* __restrict__ wAc, unsigned short* __restrict__ wAe)
{
    if (blockIdx.x < NPOS / 256) {
        int pos = blockIdx.x * 256 + threadIdx.x;
        float v[32];
#pragma unroll
        for (int ci = 0; ci < 32; ci++) v[ci] = x[ci * CSTRIDE + pos];
        unsigned dw[16];
#pragma unroll
        for (int p = 0; p < 16; p++)
            dw[p] = (unsigned)f2h(v[2 * p]) | ((unsigned)f2h(v[2 * p + 1]) << 16);
        uint4v* dst = (uint4v*)(xT + (size_t)pos * 32);
#pragma unroll
        for (int o = 0; o < 4; o++) {
            uint4v t4 = {dw[4 * o], dw[4 * o + 1], dw[4 * o + 2], dw[4 * o + 3]};
            dst[o] = t4;
        }
    } else {
        int i = (blockIdx.x - NPOS / 256) * 256 + threadIdx.x;
        if (i < 27 * 7 * 64 * 8) {                       // 96768: conv A-frags
            int j    = i & 7;
            int lane = (i >> 3) & 63;
            int fm   = i >> 9;
            int mt   = fm % 7;
            int tapw = fm / 7;                           // conv kernel tap
            int ch   = mt * 16 + (lane & 15);            // ch' = tap_o*4+comp
            int ci   = (lane >> 4) * 8 + j;
            float v = 0.f;
            if (ch < 108) {
                int tapo = ch >> 2, comp = ch & 3;
                v = (comp < 3) ? w_off[((comp * 27 + tapo) * 32 + ci) * 27 + tapw]
                               : w_mask[(tapo * 32 + ci) * 27 + tapw];
            }
            wAc[i] = f2h(v);
        } else {                                         // 27648: einsum A-frags
            int i2   = i - 27 * 7 * 64 * 8;
            int j    = i2 & 7;
            int lane = (i2 >> 3) & 63;
            int fm   = i2 >> 9;
            int mt   = fm % 2;
            int tapw = fm / 2;
            int co   = mt * 16 + (lane & 15);
            int ci   = (lane >> 4) * 8 + j;
            wAe[i2] = f2h(w[(co * 32 + ci) * 27 + tapw]);
        }
    }
}

// ---------------------------------------------------------------------------
// conv_offm v7b: A-frags via double-buffered LDS staging.
// All 4 waves read identical wAc[tap] (7168 B) — stage it ONCE per block
// (loads issued pre-barrier, ds_write post-barrier), replacing 7 VMEM
// A-loads/wave-tap with ~1.75 shared stage loads + 7 ds_reads (idle DS pipe).
// FIX vs r7: prologue tap-1 addresses were (3584+t)*8 (tap-8 data!);
// correct short offset is 3584 + t*8.
// ---------------------------------------------------------------------------
__global__ __launch_bounds__(256, 4) void conv_offm(
    const unsigned short* __restrict__ xT,
    const unsigned short* __restrict__ wAc,
    const float* __restrict__ b_off, const float* __restrict__ b_mask,
    unsigned int* __restrict__ offmH)
{
    __shared__ __align__(16) unsigned short sA[2][3584];   // 2 x 7168 B

    int bid = blockIdx.x;
    int swz = (bid & 7) * 128 + (bid >> 3);        // 8 XCD chunks of 128
    const int t = threadIdx.x, lane = t & 63;
    const int wv = t >> 6, wl = lane & 15, q = lane >> 4;
    const int row = swz * 2 + (wv >> 1);
    const int z = row >> 6, y = row & 63;
    const int xb = (wv & 1) * 32;

    // prologue: stage taps 0 and 1 (448 x 16B chunks each; thread does
    // chunks t and t+256). Tap k chunk c lives at short offset k*3584 + c*8.
    {
        uint4v v0a = *(const uint4v*)(wAc + (size_t)t * 8);
        uint4v v1a = *(const uint4v*)(wAc + 3584 + (size_t)t * 8);
        uint4v v0b, v1b;
        if (t < 192) {
            v0b = *(const uint4v*)(wAc + (size_t)(256 + t) * 8);
            v1b = *(const uint4v*)(wAc + 3584 + (size_t)(256 + t) * 8);
        }
        *(uint4v*)(&sA[0][0] + t * 8) = v0a;
        *(uint4v*)(&sA[1][0] + t * 8) = v1a;
        if (t < 192) {
            *(uint4v*)(&sA[0][0] + (256 + t) * 8) = v0b;
            *(uint4v*)(&sA[1][0] + (256 + t) * 8) = v1b;
        }
    }
    __syncthreads();

    float4v acc[7][2];
#pragma unroll
    for (int mt = 0; mt < 7; mt++)
#pragma unroll
        for (int nt = 0; nt < 2; nt++)
            acc[mt][nt] = (float4v){0.f, 0.f, 0.f, 0.f};

    for (int tap = 0; tap < 27; tap++) {
        const int p  = tap & 1;
        const int kz = tap / 9, r9 = tap - kz * 9;
        const int ky = r9 / 3,  kx = r9 - ky * 3;

        int zs = z + kz - 1;
        bool zok = (unsigned)zs < (unsigned)DD;
        int zc = min(max(zs, 0), DD - 1);
        int ys = y + ky - 1;
        bool yok = (unsigned)ys < (unsigned)HH;
        int yc = min(max(ys, 0), HH - 1);
        int rowp = (zc * HH + yc) * WW;

        // B-gathers for this tap (2 n-tiles)
        short8 b0, b1;
#pragma unroll
        for (int nt = 0; nt < 2; nt++) {
            int xs = xb + nt * 16 + wl + kx - 1;
            bool ok = zok & yok & ((unsigned)xs < (unsigned)WW);
            int xc = min(max(xs, 0), WW - 1);
            short8 bb = *(const short8*)(xT + (size_t)(rowp + xc) * 32 + q * 8);
            if (!ok) bb = (short8)0;
            if (nt == 0) b0 = bb; else b1 = bb;
        }

        // issue next-next tap's stage loads (latency hides under MFMAs)
        uint4v sva, svb;
        bool pre = (tap + 2 < 27);
        if (pre) {
            const unsigned short* src = wAc + (size_t)(tap + 2) * 3584;
            sva = *(const uint4v*)(src + (size_t)t * 8);
            if (t < 192) svb = *(const uint4v*)(src + (size_t)(256 + t) * 8);
        }

        // A-frags from LDS + MFMAs
        const unsigned short* sAp = &sA[p][0] + lane * 8;
#pragma unroll
        for (int mt = 0; mt < 7; mt++) {
            half8 a = __builtin_bit_cast(half8, *(const short8*)(sAp + mt * 512));
            acc[mt][0] = mfma16(a, __builtin_bit_cast(half8, b0), acc[mt][0]);
            acc[mt][1] = mfma16(a, __builtin_bit_cast(half8, b1), acc[mt][1]);
        }

        __syncthreads();           // all waves done reading sA[p]
        if (pre) {                 // overwrite sA[p] with tap+2
            *(uint4v*)(&sA[p][0] + t * 8) = sva;
            if (t < 192) *(uint4v*)(&sA[p][0] + (256 + t) * 8) = svb;
        }
    }

    const int rowpos = row * WW;
#pragma unroll
    for (int mt = 0; mt < 7; mt++) {
        int tapo = mt * 4 + q;
        if (tapo < 27) {
            float bz = b_off[tapo], by = b_off[27 + tapo], bx = b_off[54 + tapo];
            float bm = b_mask[tapo];
#pragma unroll
            for (int nt = 0; nt < 2; nt++) {
                float4v v = acc[mt][nt];
                float mm = v.w + bm;
                mm = 1.f / (1.f + __expf(-mm));
                int posn = rowpos + xb + nt * 16 + wl;
                uint2v pk = { pkh(v.x + bz, v.y + by), pkh(v.z + bx, mm) };
                *(uint2v*)(offmH + ((size_t)tapo * NPOS + posn) * 2) = pk;
            }
        }
    }
}

// ---------------------------------------------------------------------------
// sample_einsum v7: corner-MFMA + wAe fully staged in LDS (unchanged from
// r7 — its staging addresses were verified correct).
// ---------------------------------------------------------------------------
__global__ __launch_bounds__(256, 2) void sample_einsum(
    const unsigned short* __restrict__ xT,
    const unsigned short* __restrict__ wAe,
    const unsigned int* __restrict__ offmH,
    const float* __restrict__ bias, float* __restrict__ out)
{
    __shared__ __align__(16) unsigned short sW[27648];     // 55296 B

    int bid = blockIdx.x;
    int swz = (bid & 7) * 256 + (bid >> 3);        // 8 XCD chunks of 256 rows
    const int t = threadIdx.x, lane = t & 63;
    const int wv = t >> 6, wl = lane & 15, q = lane >> 4;
    const int d = swz >> 6, h = swz & 63;
    const int wcol = wv * 16 + wl;
    const int pos = (d * HH + h) * WW + wcol;

    // one-time stage: 3456 x 16B chunks
    for (int c = t; c < 3456; c += 256) {
        uint4v v = *(const uint4v*)(wAe + (size_t)c * 8);
        *(uint4v*)(sW + (size_t)c * 8) = v;
    }
    __syncthreads();

    const unsigned short* xTq = xT + q * 8;
    const unsigned short* sWL = sW + (size_t)lane * 8;
    float4v accA0 = (float4v){0.f, 0.f, 0.f, 0.f};
    float4v accA1 = (float4v){0.f, 0.f, 0.f, 0.f};
    float4v accB0 = (float4v){0.f, 0.f, 0.f, 0.f};
    float4v accB1 = (float4v){0.f, 0.f, 0.f, 0.f};

    // prefetch offm for tap 0
    uint2v omc = *(const uint2v*)(offmH + (size_t)pos * 2);

    for (int kz = 0; kz < 3; kz++) {
        float zbase = (float)(d + kz - 1);
#pragma unroll
        for (int j = 0; j < 9; j++) {
            const int ky = j / 3, kx = j % 3;      // compile-time
            int tap = kz * 9 + j;

            // prefetch next tap's offm (clamped -> branch-free)
            int tapn = min(tap + 1, 26);
            uint2v omn = *(const uint2v*)(offmH + ((size_t)tapn * NPOS + pos) * 2);

            float zc = zbase + h2f((unsigned short)(omc.x & 0xFFFF));
            float yc = (float)(h + ky - 1) + h2f((unsigned short)(omc.x >> 16));
            float xc = (float)(wcol + kx - 1) + h2f((unsigned short)(omc.y & 0xFFFF));
            float m  = h2f((unsigned short)(omc.y >> 16));

            float zf = floorf(zc), yf = floorf(yc), xf = floorf(xc);
            int z0 = (int)zf, y0 = (int)yf, x0 = (int)xf;
            float fz = zc - zf, fy = yc - yf, fx = xc - xf;

            float wz0 = (z0 >= 0 && z0 < DD)         ? (1.f - fz) : 0.f;
            float wz1 = (z0 + 1 >= 0 && z0 + 1 < DD) ? fz         : 0.f;
            float wy0 = (y0 >= 0 && y0 < HH)         ? (1.f - fy) : 0.f;
            float wy1 = (y0 + 1 >= 0 && y0 + 1 < HH) ? fy         : 0.f;
            float wx0 = (x0 >= 0 && x0 < WW)         ? (1.f - fx) : 0.f;
            float wx1 = (x0 + 1 >= 0 && x0 + 1 < WW) ? fx         : 0.f;

            float mz0 = m * wz0, mz1 = m * wz1;
            float a00 = mz0 * wy0, a01 = mz0 * wy1, a10 = mz1 * wy0, a11 = mz1 * wy1;
            float cw[8];
            cw[0] = a00 * wx0; cw[1] = a00 * wx1; cw[2] = a01 * wx0; cw[3] = a01 * wx1;
            cw[4] = a10 * wx0; cw[5] = a10 * wx1; cw[6] = a11 * wx0; cw[7] = a11 * wx1;

            int iz0 = min(max(z0, 0), DD - 1), iz1 = min(max(z0 + 1, 0), DD - 1);
            int iy0 = min(max(y0, 0), HH - 1), iy1 = min(max(y0 + 1, 0), HH - 1);
            int ix0 = min(max(x0, 0), WW - 1), ix1 = min(max(x0 + 1, 0), WW - 1);
            int o00 = (iz0 * HH + iy0) * WW, o01 = (iz0 * HH + iy1) * WW;
            int o10 = (iz1 * HH + iy0) * WW, o11 = (iz1 * HH + iy1) * WW;

            short8 cnr[8];
            cnr[0] = *(const short8*)(xTq + (o00 + ix0) * 32);
            cnr[1] = *(const short8*)(xTq + (o00 + ix1) * 32);
            cnr[2] = *(const short8*)(xTq + (o01 + ix0) * 32);
            cnr[3] = *(const short8*)(xTq + (o01 + ix1) * 32);
            cnr[4] = *(const short8*)(xTq + (o10 + ix0) * 32);
            cnr[5] = *(const short8*)(xTq + (o10 + ix1) * 32);
            cnr[6] = *(const short8*)(xTq + (o11 + ix0) * 32);
            cnr[7] = *(const short8*)(xTq + (o11 + ix1) * 32);

            // A-frags from LDS (DS pipe)
            const unsigned short* aep = sWL + (size_t)tap * 1024;
            half8 a0 = __builtin_bit_cast(half8, *(const short8*)(aep));
            half8 a1 = __builtin_bit_cast(half8, *(const short8*)(aep + 512));

#pragma unroll
            for (int c = 0; c < 8; c++) {
                _Float16 ch = (_Float16)cw[c];
                half8 bh = __builtin_bit_cast(half8, cnr[c]) * ch;   // 4x v_pk_mul_f16
                if (c < 4) {
                    accA0 = mfma16(a0, bh, accA0);
                    accA1 = mfma16(a1, bh, accA1);
                } else {
                    accB0 = mfma16(a0, bh, accB0);
                    accB1 = mfma16(a1, bh, accB1);
                }
            }

            omc = omn;
        }
    }

    // epilogue: merge accumulator banks; C/D layout col = lane&15, row = q*4+r
    int sp = pos;
#pragma unroll
    for (int r = 0; r < 4; r++) {
        int co0 = q * 4 + r;
        out[co0 * CSTRIDE + sp]        = accA0[r] + accB0[r] + bias[co0];
        out[(16 + co0) * CSTRIDE + sp] = accA1[r] + accB1[r] + bias[16 + co0];
    }
}

// ---------------------------------------------------------------------------
extern "C" void kernel_launch(void* const* d_in, const int* in_sizes, int n_in,
                              void* d_out, int out_size, void* d_ws, size_t ws_size,
                              hipStream_t stream) {
    const float* x      = (const float*)d_in[0];
    const float* w_off  = (const float*)d_in[1];
    const float* b_off  = (const float*)d_in[2];
    const float* w_mask = (const float*)d_in[3];
    const float* b_mask = (const float*)d_in[4];
    const float* w      = (const float*)d_in[5];
    const float* b      = (const float*)d_in[6];
    float* out = (float*)d_out;

    // workspace layout (16B aligned, ~37.0 MB total):
    //   xT    8,388,608 B   fp16 x[pos][32ch]
    //   wAc     193,536 B   conv A-frags (fp16)
    //   wAe      55,296 B   einsum A-frags (fp16)
    //   offmH 28,311,552 B  fp16x4 {oz,oy,ox,mask}[tap][pos]
    unsigned short* xT  = (unsigned short*)d_ws;
    unsigned short* wAc = xT + (size_t)NPOS * 32;
    unsigned short* wAe = wAc + 27 * 7 * 64 * 8;
    unsigned int* offmH = (unsigned int*)(wAe + 27 * 2 * 64 * 8);

    hipLaunchKernelGGL(prep_all, dim3(NPOS / 256 + 486), dim3(256), 0, stream,
                       x, xT, w_off, w_mask, w, wAc, wAe);
    hipLaunchKernelGGL(conv_offm, dim3(1024), dim3(256), 0, stream,
                       xT, wAc, b_off, b_mask, offmH);
    hipLaunchKernelGGL(sample_einsum, dim3(2048), dim3(256), 0, stream,
                       xT, wAe, offmH, b, out);
}